// Round 1
// baseline (682.129 us; speedup 1.0000x reference)
//
#include <hip/hip_runtime.h>
#include <math.h>

#define N_BINS 15
#define C 50
#define RPB 256              // rows per block == block size
#define PAD 51               // LDS row stride (odd -> conflict-free b32 reads)

// ws layout: uint cnt[15] | uint acc[15] | float conf[15]   (180 bytes)

__global__ __launch_bounds__(RPB) void ece_accum(
    const float* __restrict__ logits,
    const int*   __restrict__ labels,
    unsigned int* __restrict__ ws_cnt,
    unsigned int* __restrict__ ws_acc,
    float*        __restrict__ ws_conf,
    int n_rows)
{
    __shared__ float tile[RPB * PAD];          // 52224 B
    __shared__ unsigned int s_cnt[N_BINS];
    __shared__ unsigned int s_acc[N_BINS];
    __shared__ float        s_conf[N_BINS];

    const int tid = threadIdx.x;
    if (tid < N_BINS) { s_cnt[tid] = 0u; s_acc[tid] = 0u; s_conf[tid] = 0.0f; }

    const long long row0 = (long long)blockIdx.x * RPB;
    const float* __restrict__ src = logits + row0 * C;
    const long long rem_rows = (long long)n_rows - row0;
    const int rows_here = (rem_rows >= RPB) ? RPB : (int)(rem_rows > 0 ? rem_rows : 0);

    if (rows_here == RPB) {
        // full tile: coalesced float4 staging, 12800 floats = 3200 float4
        const float4* __restrict__ src4 = (const float4*)src;
        for (int i = tid; i < (RPB * C) / 4; i += RPB) {
            float4 v = src4[i];
            int base = 4 * i;
            int r    = base / C;          // magic-mul divide
            int rem  = base - r * C;
            int addr = base + r;          // == r*PAD + rem
            if (rem <= C - 4) {
                tile[addr]     = v.x;
                tile[addr + 1] = v.y;
                tile[addr + 2] = v.z;
                tile[addr + 3] = v.w;
            } else {                      // float4 spans a row boundary (rem == 48)
                float e[4] = {v.x, v.y, v.z, v.w};
                #pragma unroll
                for (int j = 0; j < 4; ++j) {
                    int ee = base + j;
                    tile[ee + ee / C] = e[j];
                }
            }
        }
    } else {
        int tot = rows_here * C;
        for (int i = tid; i < tot; i += RPB) tile[i + i / C] = src[i];
    }
    __syncthreads();

    const long long row = row0 + tid;
    if (row < (long long)n_rows && tid < rows_here) {
        const float* __restrict__ r = &tile[tid * PAD];
        float vals[C];
        float vmax = -INFINITY;
        int   amax = 0;
        #pragma unroll
        for (int k = 0; k < C; ++k) {
            float v = r[k];
            vals[k] = v;
            if (v > vmax) { vmax = v; amax = k; }   // first-max kept, matches argmax
        }
        float sum = 0.0f;
        #pragma unroll
        for (int k = 0; k < C; ++k) sum += __expf(vals[k] - vmax);
        float conf = 1.0f / sum;                    // == max(softmax(row))

        int bin = (int)ceilf(conf * 15.0f) - 1;     // searchsorted(uppers, conf, left)
        bin = bin < 0 ? 0 : (bin > N_BINS - 1 ? N_BINS - 1 : bin);

        int correct = (amax == labels[row]) ? 1 : 0;

        atomicAdd(&s_cnt[bin], 1u);
        if (correct) atomicAdd(&s_acc[bin], 1u);
        atomicAdd(&s_conf[bin], conf);
    }
    __syncthreads();

    if (tid < N_BINS && s_cnt[tid] != 0u) {
        atomicAdd(&ws_cnt[tid], s_cnt[tid]);
        atomicAdd(&ws_acc[tid], s_acc[tid]);
        atomicAdd(&ws_conf[tid], s_conf[tid]);
    }
}

__global__ __launch_bounds__(64) void ece_final(
    const unsigned int* __restrict__ ws_cnt,
    const unsigned int* __restrict__ ws_acc,
    const float*        __restrict__ ws_conf,
    float* __restrict__ out, float inv_n)
{
    int i = threadIdx.x;
    float v = 0.0f;
    if (i < N_BINS) {
        float cnt      = (float)ws_cnt[i];          // exact (< 2^24)
        float prop     = cnt * inv_n;               // inv_n = 2^-21, exact scale
        float denom    = fmaxf(cnt, 1.0f);
        float avg_acc  = (float)ws_acc[i] / denom;
        float avg_conf = ws_conf[i] / denom;
        float gap      = avg_conf - avg_acc;
        bool  nonempty = cnt > 0.0f;
        out[1 + i]  = nonempty ? gap * prop : 0.0f;   // bin_over_confidence
        out[16 + i] = prop;                            // prop_in_bin
        v = nonempty ? fabsf(gap) * prop : 0.0f;
    }
    // reduce lanes 0..15 (others carry 0)
    v += __shfl_down(v, 8, 64);
    v += __shfl_down(v, 4, 64);
    v += __shfl_down(v, 2, 64);
    v += __shfl_down(v, 1, 64);
    if (i == 0) out[0] = v;                            // ece
}

extern "C" void kernel_launch(void* const* d_in, const int* in_sizes, int n_in,
                              void* d_out, int out_size, void* d_ws, size_t ws_size,
                              hipStream_t stream)
{
    const float* logits = (const float*)d_in[0];
    const int*   labels = (const int*)d_in[1];
    const int n_rows = in_sizes[1];                    // C = in_sizes[0]/in_sizes[1] = 50

    unsigned int* ws_cnt  = (unsigned int*)d_ws;
    unsigned int* ws_acc  = ws_cnt + N_BINS;
    float*        ws_conf = (float*)(ws_acc + N_BINS);

    hipMemsetAsync(d_ws, 0, 3 * N_BINS * sizeof(float), stream);

    int grid = (n_rows + RPB - 1) / RPB;
    ece_accum<<<grid, RPB, 0, stream>>>(logits, labels, ws_cnt, ws_acc, ws_conf, n_rows);
    ece_final<<<1, 64, 0, stream>>>(ws_cnt, ws_acc, ws_conf, (float*)d_out,
                                    1.0f / (float)n_rows);
}

// Round 2
// 553.271 us; speedup vs baseline: 1.2329x; 1.2329x over previous
//
#include <hip/hip_runtime.h>
#include <math.h>

#define N_BINS 15
#define C 50
#define ROWS_PER_TILE 64                   // rows staged per wave-iteration
#define TILE_FLOATS (ROWS_PER_TILE * C)    // 3200 floats = 12800 B
#define WAVES_PER_BLOCK 4
#define BLOCK (WAVES_PER_BLOCK * 64)
#define GRID 768                           // 3 blocks/CU * 256 CU, fully resident

// ws layout: uint cnt[15] | uint acc[15] | float conf[15]

__device__ __forceinline__ void load_lds16(const float* g, float* l) {
    // async global->LDS DMA, 16B/lane; LDS dest = wave-uniform base + lane*16
    __builtin_amdgcn_global_load_lds(
        (const __attribute__((address_space(1))) unsigned int*)g,
        (__attribute__((address_space(3))) unsigned int*)l, 16, 0, 0);
}

__global__ __launch_bounds__(BLOCK) void ece_accum(
    const float* __restrict__ logits,
    const int*   __restrict__ labels,
    unsigned int* __restrict__ ws_cnt,
    unsigned int* __restrict__ ws_acc,
    float*        __restrict__ ws_conf,
    int n_rows)
{
    __shared__ float tiles[WAVES_PER_BLOCK * TILE_FLOATS];   // 51200 B, unpadded
    __shared__ unsigned int s_cnt[N_BINS];
    __shared__ unsigned int s_acc[N_BINS];
    __shared__ float        s_conf[N_BINS];

    const int tid = threadIdx.x;
    if (tid < N_BINS) { s_cnt[tid] = 0u; s_acc[tid] = 0u; s_conf[tid] = 0.0f; }
    __syncthreads();

    const int wave = tid >> 6;
    const int lane = tid & 63;
    float* __restrict__ wtile = &tiles[wave * TILE_FLOATS];

    const int n_tiles  = n_rows / ROWS_PER_TILE;          // 32768 (exact here)
    const int gwave    = blockIdx.x * WAVES_PER_BLOCK + wave;
    const int n_gwaves = GRID * WAVES_PER_BLOCK;          // 3072

    for (int t = gwave; t < n_tiles; t += n_gwaves) {
        const float* __restrict__ src = logits + (size_t)t * TILE_FLOATS;

        // drain prior ds_reads before the DMA overwrites this wave's tile (WAR)
        asm volatile("s_waitcnt lgkmcnt(0)" ::: "memory");

        // stage 12800 B = 800 float4: 12 full-wave DMAs + 1 half-wave DMA,
        // all fire-and-forget -> 13 KB in flight per wave
        #pragma unroll
        for (int j = 0; j < 12; ++j)
            load_lds16(src + (j * 64 + lane) * 4, wtile + j * 256);
        if (lane < 32)
            load_lds16(src + (12 * 64 + lane) * 4, wtile + 12 * 256);

        int label = labels[t * ROWS_PER_TILE + lane];     // coalesced b32

        asm volatile("s_waitcnt vmcnt(0)" ::: "memory");  // DMA + label complete

        // row `lane` of this tile, contiguous 50 floats (200 B, 8B-aligned)
        const float2* __restrict__ r2 = (const float2*)(wtile + lane * C);
        float vals[C];
        #pragma unroll
        for (int k = 0; k < C / 2; ++k) {
            float2 p = r2[k];
            vals[2 * k]     = p.x;
            vals[2 * k + 1] = p.y;
        }

        float vmax = vals[0];
        int   amax = 0;
        #pragma unroll
        for (int k = 1; k < C; ++k)
            if (vals[k] > vmax) { vmax = vals[k]; amax = k; }  // first max kept

        float sum = 0.0f;
        #pragma unroll
        for (int k = 0; k < C; ++k) sum += __expf(vals[k] - vmax);
        float conf = 1.0f / sum;                // == max(softmax(row))

        int bin = (int)ceilf(conf * 15.0f) - 1; // searchsorted(uppers, conf, left)
        bin = bin < 0 ? 0 : (bin > N_BINS - 1 ? N_BINS - 1 : bin);

        atomicAdd(&s_cnt[bin], 1u);
        if (amax == label) atomicAdd(&s_acc[bin], 1u);
        atomicAdd(&s_conf[bin], conf);
    }

    // leftover rows (n_rows % 64) — scalar path, block 0 only (0 for this shape)
    const int rem_start = n_tiles * ROWS_PER_TILE;
    const int rem = n_rows - rem_start;
    if (blockIdx.x == 0 && tid < rem) {
        const float* __restrict__ r = logits + (size_t)(rem_start + tid) * C;
        float vmax = r[0];
        int   amax = 0;
        for (int k = 1; k < C; ++k) {
            float v = r[k];
            if (v > vmax) { vmax = v; amax = k; }
        }
        float sum = 0.0f;
        for (int k = 0; k < C; ++k) sum += __expf(r[k] - vmax);
        float conf = 1.0f / sum;
        int bin = (int)ceilf(conf * 15.0f) - 1;
        bin = bin < 0 ? 0 : (bin > N_BINS - 1 ? N_BINS - 1 : bin);
        atomicAdd(&s_cnt[bin], 1u);
        if (amax == labels[rem_start + tid]) atomicAdd(&s_acc[bin], 1u);
        atomicAdd(&s_conf[bin], conf);
    }

    __syncthreads();
    if (tid < N_BINS && s_cnt[tid] != 0u) {
        atomicAdd(&ws_cnt[tid],  s_cnt[tid]);
        atomicAdd(&ws_acc[tid],  s_acc[tid]);
        atomicAdd(&ws_conf[tid], s_conf[tid]);
    }
}

__global__ __launch_bounds__(64) void ece_final(
    const unsigned int* __restrict__ ws_cnt,
    const unsigned int* __restrict__ ws_acc,
    const float*        __restrict__ ws_conf,
    float* __restrict__ out, float inv_n)
{
    int i = threadIdx.x;
    float v = 0.0f;
    if (i < N_BINS) {
        float cnt      = (float)ws_cnt[i];      // exact (< 2^24)
        float prop     = cnt * inv_n;
        float denom    = fmaxf(cnt, 1.0f);
        float avg_acc  = (float)ws_acc[i] / denom;
        float avg_conf = ws_conf[i] / denom;
        float gap      = avg_conf - avg_acc;
        bool  nonempty = cnt > 0.0f;
        out[1 + i]  = nonempty ? gap * prop : 0.0f;   // bin_over_confidence
        out[16 + i] = prop;                            // prop_in_bin
        v = nonempty ? fabsf(gap) * prop : 0.0f;
    }
    v += __shfl_down(v, 8, 64);
    v += __shfl_down(v, 4, 64);
    v += __shfl_down(v, 2, 64);
    v += __shfl_down(v, 1, 64);
    if (i == 0) out[0] = v;                            // ece
}

extern "C" void kernel_launch(void* const* d_in, const int* in_sizes, int n_in,
                              void* d_out, int out_size, void* d_ws, size_t ws_size,
                              hipStream_t stream)
{
    const float* logits = (const float*)d_in[0];
    const int*   labels = (const int*)d_in[1];
    const int n_rows = in_sizes[1];

    unsigned int* ws_cnt  = (unsigned int*)d_ws;
    unsigned int* ws_acc  = ws_cnt + N_BINS;
    float*        ws_conf = (float*)(ws_acc + N_BINS);

    hipMemsetAsync(d_ws, 0, 3 * N_BINS * sizeof(float), stream);

    ece_accum<<<GRID, BLOCK, 0, stream>>>(logits, labels, ws_cnt, ws_acc, ws_conf, n_rows);
    ece_final<<<1, 64, 0, stream>>>(ws_cnt, ws_acc, ws_conf, (float*)d_out,
                                    1.0f / (float)n_rows);
}